// Round 10
// baseline (545.403 us; speedup 1.0000x reference)
//
#include <hip/hip_runtime.h>

#define N_NODES 100000
#define N_EDGES 1600000
#define N_GRAPHS 64
#define IN_F 128
#define HID 256
#define OUT_F 10

#define SCAN_B 1024
#define SCAN_NB ((N_NODES + SCAN_B - 1) / SCAN_B)   // 98

typedef __attribute__((ext_vector_type(8))) short short8v;
typedef __attribute__((ext_vector_type(4))) float f32x4;

__device__ __forceinline__ unsigned short f2bf(float f) {
    unsigned int u = __float_as_uint(f);
    u += 0x7FFFu + ((u >> 16) & 1u);   // round-to-nearest-even
    return (unsigned short)(u >> 16);
}
__device__ __forceinline__ float bf2f(unsigned short s) {
    return __uint_as_float((unsigned int)s << 16);
}

// ---------------- CSR build ----------------
__global__ void k_count(const int* __restrict__ dst, int* __restrict__ cnt) {
    int e = blockIdx.x * blockDim.x + threadIdx.x;
    if (e < N_EDGES) atomicAdd(&cnt[dst[e]], 1);
}

// f32 -> bf16 bulk convert, both weight matrices in one launch
__global__ void k_tobf2(const float* __restrict__ w1, unsigned short* __restrict__ w1b, int n1_8,
                        const float* __restrict__ w2, unsigned short* __restrict__ w2b, int n2_8) {
    int t = blockIdx.x * blockDim.x + threadIdx.x;
    const float* p;
    unsigned short* o;
    if (t < n1_8) { p = w1 + (size_t)t * 8; o = w1b + (size_t)t * 8; }
    else if (t < n1_8 + n2_8) { int u = t - n1_8; p = w2 + (size_t)u * 8; o = w2b + (size_t)u * 8; }
    else return;
    float4 a = *(const float4*)p;
    float4 b = *(const float4*)(p + 4);
    unsigned int o0 = f2bf(a.x) | ((unsigned int)f2bf(a.y) << 16);
    unsigned int o1 = f2bf(a.z) | ((unsigned int)f2bf(a.w) << 16);
    unsigned int o2 = f2bf(b.x) | ((unsigned int)f2bf(b.y) << 16);
    unsigned int o3 = f2bf(b.z) | ((unsigned int)f2bf(b.w) << 16);
    *(uint4*)o = make_uint4(o0, o1, o2, o3);
}

// prescaled bf16 copy of x: xb[i][c] = bf16(x[i][c] * dinv[i])
__global__ void k_xtobf(const float* __restrict__ x, const float* __restrict__ dinv,
                        unsigned short* __restrict__ xb) {
    int t = blockIdx.x * blockDim.x + threadIdx.x;
    if (t >= N_NODES * (IN_F / 8)) return;
    int node = t / (IN_F / 8);
    float sc = dinv[node];
    const float* p = x + (size_t)t * 8;
    float4 a = *(const float4*)p;
    float4 b = *(const float4*)(p + 4);
    unsigned int o0 = f2bf(a.x * sc) | ((unsigned int)f2bf(a.y * sc) << 16);
    unsigned int o1 = f2bf(a.z * sc) | ((unsigned int)f2bf(a.w * sc) << 16);
    unsigned int o2 = f2bf(b.x * sc) | ((unsigned int)f2bf(b.y * sc) << 16);
    unsigned int o3 = f2bf(b.z * sc) | ((unsigned int)f2bf(b.w * sc) << 16);
    *(uint4*)(xb + (size_t)t * 8) = make_uint4(o0, o1, o2, o3);
}

// multi-block exclusive scan; also writes dinv = rsqrt(cnt+1)
__global__ void k_scan1(const int* __restrict__ cnt, int* __restrict__ rowptr,
                        int* __restrict__ bsum, float* __restrict__ dinv) {
    __shared__ int sm[SCAN_B];
    int t = threadIdx.x, base = blockIdx.x * SCAN_B;
    int v = (base + t < N_NODES) ? cnt[base + t] : 0;
    if (base + t < N_NODES) dinv[base + t] = rsqrtf((float)v + 1.0f);
    int x = v;
    sm[t] = x;
    __syncthreads();
    for (int off = 1; off < SCAN_B; off <<= 1) {
        int add = (t >= off) ? sm[t - off] : 0;
        __syncthreads();
        x += add;
        sm[t] = x;
        __syncthreads();
    }
    if (base + t < N_NODES) rowptr[base + t] = x - v;
    if (t == SCAN_B - 1) bsum[blockIdx.x] = x;
}

__global__ void k_scan2(int* __restrict__ bsum) {
    __shared__ int sm[128];
    int t = threadIdx.x;
    int v = (t < SCAN_NB) ? bsum[t] : 0;
    int x = v;
    sm[t] = x;
    __syncthreads();
    for (int off = 1; off < 128; off <<= 1) {
        int add = (t >= off) ? sm[t - off] : 0;
        __syncthreads();
        x += add;
        sm[t] = x;
        __syncthreads();
    }
    if (t < SCAN_NB) bsum[t] = x - v;
}

__global__ void k_scan3(int* __restrict__ rowptr, const int* __restrict__ bsum) {
    int i = blockIdx.x * blockDim.x + threadIdx.x;
    if (i < N_NODES) rowptr[i] += bsum[i >> 10];
}

__global__ void k_fill(const int* __restrict__ src, const int* __restrict__ dst,
                       const int* __restrict__ rowptr, int* __restrict__ fill,
                       int* __restrict__ col) {
    int e = blockIdx.x * blockDim.x + threadIdx.x;
    if (e >= N_EDGES) return;
    int d = dst[e];
    int p = rowptr[d] + atomicAdd(&fill[d], 1);
    col[p] = src[e];
}

// ---------------- aggregation: XCD-pinned column slices via work queues ----------------
// out[i][slice] = bf16( dinv[i] * (hb[i] + sum_j hb[j]) )[slice], rows prescaled bf16.
// Feature dim split into 2 slices of SW. Two atomic queues (one per slice); each
// block reads its REAL XCD id (s_getreg HW_REG_XCC_ID) and prefers the queue
// matching its XCD half, falling back to the other -> correct under ANY mapping,
// fast when XCDs 0-3 take slice 0 and 4-7 take slice 1 (per-XCD L2 fill halves).
// Work unit = 128 consecutive nodes x one slice. Wave sub-groups of LR lanes
// gather one row each with 16B/lane uint4 loads, U deep.
template<int W, int SW, int U>
__global__ void __launch_bounds__(256)
k_aggq(const unsigned short* __restrict__ hb, const float* __restrict__ dinv,
       const int* __restrict__ rowptr, const int* __restrict__ cnt,
       const int* __restrict__ col, unsigned short* __restrict__ out,
       int* __restrict__ q, int nch) {
    constexpr int LR = SW / 8;         // lanes per row slice
    constexpr int NW = 64 / LR;        // rows per wave per step
    __shared__ int sh_c, sh_s;
    if (threadIdx.x == 0) {
        int xcc;
        asm volatile("s_getreg_b32 %0, hwreg(HW_REG_XCC_ID)" : "=s"(xcc));
        int pref = (xcc >> 2) & 1;     // XCD 0-3 -> 0, 4-7 -> 1
        int c = atomicAdd(&q[pref], 1);
        int sl = pref;
        if (c >= nch) { c = atomicAdd(&q[1 ^ pref], 1); sl ^= 1; }
        sh_c = c; sh_s = sl;
    }
    __syncthreads();
    int chunk = sh_c, slice = sh_s;
    if (chunk >= nch) return;          // both queues drained
    int wid = threadIdx.x >> 6, lane = threadIdx.x & 63;
    int g = lane / LR;                 // neighbor slot within wave
    int s8 = (lane % LR) * 8;          // bf16 col within slice
    const unsigned short* hbs = hb + slice * SW + s8;
    for (int it = 0; it < 32; ++it) {
        int i = chunk * 128 + it * 4 + wid;     // wave-uniform
        if (i >= N_NODES) break;
        float dd = dinv[i];
        int beg = rowptr[i] - 1;       // virtual v: 0 -> self, v>=1 -> col[beg+v]
        int total = cnt[i] + 1;
        float acc[8] = {};
        for (int v = 0; v < total; v += U * NW) {
            uint4 d[U];
            #pragma unroll
            for (int u = 0; u < U; ++u) {
                int idx = v + u * NW + g;
                d[u] = make_uint4(0u, 0u, 0u, 0u);
                if (idx < total) {
                    int r = (idx == 0) ? i : col[beg + idx];
                    d[u] = *(const uint4*)(hbs + (size_t)r * W);
                }
            }
            #pragma unroll
            for (int u = 0; u < U; ++u) {
                acc[0] += bf2f((unsigned short)(d[u].x & 0xffffu));
                acc[1] += bf2f((unsigned short)(d[u].x >> 16));
                acc[2] += bf2f((unsigned short)(d[u].y & 0xffffu));
                acc[3] += bf2f((unsigned short)(d[u].y >> 16));
                acc[4] += bf2f((unsigned short)(d[u].z & 0xffffu));
                acc[5] += bf2f((unsigned short)(d[u].z >> 16));
                acc[6] += bf2f((unsigned short)(d[u].w & 0xffffu));
                acc[7] += bf2f((unsigned short)(d[u].w >> 16));
            }
        }
        #pragma unroll
        for (int off = LR; off < 64; off <<= 1)
            #pragma unroll
            for (int c = 0; c < 8; ++c)
                acc[c] += __shfl_xor(acc[c], off, 64);
        if (g == 0) {
            unsigned int o0 = f2bf(dd * acc[0]) | ((unsigned int)f2bf(dd * acc[1]) << 16);
            unsigned int o1 = f2bf(dd * acc[2]) | ((unsigned int)f2bf(dd * acc[3]) << 16);
            unsigned int o2 = f2bf(dd * acc[4]) | ((unsigned int)f2bf(dd * acc[5]) << 16);
            unsigned int o3 = f2bf(dd * acc[6]) | ((unsigned int)f2bf(dd * acc[7]) << 16);
            *(uint4*)(out + (size_t)i * W + slice * SW + s8) = make_uint4(o0, o1, o2, o3);
        }
    }
}

// ---------------- MFMA GEMM: relu(A @ W^T + bias); A:[M,K] bf16, W:[256,K] bf16 ----------------
template<int K, bool FUSE>
__global__ void __launch_bounds__(256)
k_mgemm(const unsigned short* __restrict__ A, const unsigned short* __restrict__ Wb,
        const float* __restrict__ bias, unsigned short* __restrict__ Cb,
        const float* __restrict__ dinv, const int* __restrict__ batch,
        float* __restrict__ pooled) {
    constexpr int LDT = 72;   // padded row stride (shorts)
    __shared__ unsigned short Asl[128 * LDT];
    __shared__ unsigned short Bsl[128 * LDT];
    __shared__ float red[128];
    int row0 = blockIdx.x * 128;
    int col0 = blockIdx.y * 128;
    int t = threadIdx.x;
    int wid = t >> 6, lane = t & 63;
    int fr = lane & 15, fq = lane >> 4;
    int wr = wid >> 1, wc = wid & 1;

    f32x4 acc[4][4] = {};

    for (int kc = 0; kc < K; kc += 64) {
        #pragma unroll
        for (int p = 0; p < 4; ++p) {
            int idx = p * 256 + t;            // 0..1023
            int r = idx >> 3;                 // 0..127
            int c8 = (idx & 7) * 8;           // bf16 col
            uint4 v = make_uint4(0u, 0u, 0u, 0u);
            int grow = row0 + r;
            if (grow < N_NODES) v = *(const uint4*)(A + (size_t)grow * K + kc + c8);
            *(uint4*)(Asl + r * LDT + c8) = v;
            uint4 w = *(const uint4*)(Wb + (size_t)(col0 + r) * K + kc + c8);
            *(uint4*)(Bsl + r * LDT + c8) = w;
        }
        __syncthreads();
        #pragma unroll
        for (int k0 = 0; k0 < 64; k0 += 32) {
            short8v af[4], bf[4];
            #pragma unroll
            for (int m = 0; m < 4; ++m)
                af[m] = *(const short8v*)(Asl + (wr * 64 + m * 16 + fr) * LDT + k0 + fq * 8);
            #pragma unroll
            for (int n = 0; n < 4; ++n)
                bf[n] = *(const short8v*)(Bsl + (wc * 64 + n * 16 + fr) * LDT + k0 + fq * 8);
            #pragma unroll
            for (int m = 0; m < 4; ++m)
                #pragma unroll
                for (int n = 0; n < 4; ++n)
                    acc[m][n] = __builtin_amdgcn_mfma_f32_16x16x32_bf16(af[m], bf[n], acc[m][n], 0, 0, 0);
        }
        __syncthreads();
    }

    float bv[4];
    #pragma unroll
    for (int n = 0; n < 4; ++n) bv[n] = bias[col0 + wc * 64 + n * 16 + fr];

    if (!FUSE) {
        #pragma unroll
        for (int m = 0; m < 4; ++m) {
            #pragma unroll
            for (int j = 0; j < 4; ++j) {
                int row = row0 + wr * 64 + m * 16 + fq * 4 + j;
                if (row >= N_NODES) continue;
                float sc = dinv[row];
                unsigned short* o = Cb + (size_t)row * HID + col0 + wc * 64;
                #pragma unroll
                for (int n = 0; n < 4; ++n) {
                    float v = fmaxf(acc[m][n][j] + bv[n], 0.f) * sc;
                    o[n * 16 + fr] = f2bf(v);
                }
            }
        }
    } else {
        int gm[4][4];
        #pragma unroll
        for (int m = 0; m < 4; ++m)
            #pragma unroll
            for (int j = 0; j < 4; ++j) {
                int row = row0 + wr * 64 + m * 16 + fq * 4 + j;
                gm[m][j] = (row < N_NODES) ? batch[row] : -1;
                #pragma unroll
                for (int n = 0; n < 4; ++n)
                    acc[m][n][j] = fmaxf(acc[m][n][j] + bv[n], 0.f);
            }
        int rhi = row0 + 127; if (rhi >= N_NODES) rhi = N_NODES - 1;
        int glo = batch[row0], ghi = batch[rhi];
        for (int g = glo; g <= ghi; ++g) {
            if (t < 128) red[t] = 0.f;
            __syncthreads();
            #pragma unroll
            for (int n = 0; n < 4; ++n) {
                float s = 0.f;
                #pragma unroll
                for (int m = 0; m < 4; ++m)
                    #pragma unroll
                    for (int j = 0; j < 4; ++j)
                        if (gm[m][j] == g) s += acc[m][n][j];
                if (s != 0.f) atomicAdd(&red[wc * 64 + n * 16 + fr], s);
            }
            __syncthreads();
            if (t < 128 && red[t] != 0.f)
                atomicAdd(&pooled[g * HID + col0 + t], red[t]);
            __syncthreads();
        }
    }
}

// ---------------- final FC (per-graph counts via inline binary search) ----------------
__global__ void k_final(const float* __restrict__ pooled, const int* __restrict__ batch,
                        const float* __restrict__ Wfc, const float* __restrict__ bfc,
                        float* __restrict__ out) {
    int t = blockIdx.x * blockDim.x + threadIdx.x;
    if (t >= N_GRAPHS * OUT_F) return;
    int g = t / OUT_F, o = t % OUT_F;
    int lo = 0, hi = N_NODES;
    while (lo < hi) { int mid = (lo + hi) >> 1; if (batch[mid] < g) lo = mid + 1; else hi = mid; }
    int a = lo;
    lo = 0; hi = N_NODES;
    while (lo < hi) { int mid = (lo + hi) >> 1; if (batch[mid] < g + 1) lo = mid + 1; else hi = mid; }
    float inv = 1.0f / fmaxf((float)(lo - a), 1.0f);
    float s = 0.f;
    for (int k = 0; k < HID; ++k) s += pooled[g * HID + k] * Wfc[o * HID + k];
    out[t] = s * inv + bfc[o];
}

extern "C" void kernel_launch(void* const* d_in, const int* in_sizes, int n_in,
                              void* d_out, int out_size, void* d_ws, size_t ws_size,
                              hipStream_t stream) {
    const float* x    = (const float*)d_in[0];
    const int*   ei   = (const int*)d_in[1];
    const int*   bat  = (const int*)d_in[2];
    const float* W1   = (const float*)d_in[3];
    const float* b1   = (const float*)d_in[4];
    const float* W2   = (const float*)d_in[5];
    const float* b2   = (const float*)d_in[6];
    const float* Wfc  = (const float*)d_in[7];
    const float* bfc  = (const float*)d_in[8];
    float* out = (float*)d_out;

    const int* src = ei;
    const int* dst = ei + N_EDGES;

    float* ws = (float*)d_ws;
    float* dinv    = ws + 0;                 // 100096
    float* pooled  = ws + 100096;            // 16384
    int*   cnt     = (int*)(ws + 116608);    // 100096
    int*   rowptr  = (int*)(ws + 216704);    // 100224
    int*   fill    = (int*)(ws + 316928);    // 100000
    int*   bsum    = (int*)(ws + 416928);    // 98 used (112..127 free)
    int*   q1      = (int*)(ws + 417040);    // 2 (layer-1 queues)
    int*   q2      = (int*)(ws + 417048);    // 2 (layer-2 queues)
    int*   col     = (int*)(ws + 417056);    // 1600000
    unsigned short* W1b = (unsigned short*)(ws + 2017056);   // 32768 bf16
    unsigned short* W2b = (unsigned short*)(ws + 2033440);   // 65536 bf16
    unsigned short* xb  = (unsigned short*)(ws + 2066208);   // 100000*128 bf16
    unsigned short* h1b = (unsigned short*)(ws + 8466208);   // 100000*256 bf16
    unsigned short* aggb = (unsigned short*)(ws + 21266208); // up to 100000*256 bf16

    const int B = 256;

    // single contiguous zero: pooled .. q2 (excludes col)
    hipMemsetAsync(pooled, 0, (size_t)(417056 - 100096) * 4, stream);

    k_count<<<(N_EDGES + B - 1) / B, B, 0, stream>>>(dst, cnt);
    k_scan1<<<SCAN_NB, SCAN_B, 0, stream>>>(cnt, rowptr, bsum, dinv);
    k_scan2<<<1, 128, 0, stream>>>(bsum);
    k_scan3<<<(N_NODES + B - 1) / B, B, 0, stream>>>(rowptr, bsum);
    k_tobf2<<<((HID * IN_F + HID * HID) / 8 + B - 1) / B, B, 0, stream>>>(
        W1, W1b, HID * IN_F / 8, W2, W2b, HID * HID / 8);
    k_xtobf<<<(N_NODES * (IN_F / 8) + B - 1) / B, B, 0, stream>>>(x, dinv, xb);
    k_fill<<<(N_EDGES + B - 1) / B, B, 0, stream>>>(src, dst, rowptr, fill, col);

    const int NCH = (N_NODES + 127) / 128;   // 782 chunks per slice

    // layer 1: aggb = bf16(A_hat @ x), h1b = bf16(relu(aggb@W1^T+b1)*dinv)
    k_aggq<IN_F, 64, 4><<<2 * NCH, 256, 0, stream>>>(xb, dinv, rowptr, cnt, col, aggb, q1, NCH);
    {
        dim3 grid((N_NODES + 127) / 128, HID / 128);
        k_mgemm<IN_F, false><<<grid, 256, 0, stream>>>(aggb, W1b, b1, h1b, dinv, nullptr, nullptr);
    }

    // layer 2: aggb = bf16(A_hat @ h1), pooled += relu(aggb@W2^T+b2) segment-reduced
    k_aggq<HID, 128, 4><<<2 * NCH, 256, 0, stream>>>(h1b, dinv, rowptr, cnt, col, aggb, q2, NCH);
    {
        dim3 grid((N_NODES + 127) / 128, HID / 128);
        k_mgemm<HID, true><<<grid, 256, 0, stream>>>(aggb, W2b, b2, nullptr, nullptr, bat, pooled);
    }

    k_final<<<(N_GRAPHS * OUT_F + B - 1) / B, B, 0, stream>>>(pooled, bat, Wfc, bfc, out);
}

// Round 11
// 480.898 us; speedup vs baseline: 1.1341x; 1.1341x over previous
//
#include <hip/hip_runtime.h>

#define N_NODES 100000
#define N_EDGES 1600000
#define N_GRAPHS 64
#define IN_F 128
#define HID 256
#define OUT_F 10

#define SCAN_B 1024
#define SCAN_NB ((N_NODES + SCAN_B - 1) / SCAN_B)   // 98

typedef __attribute__((ext_vector_type(8))) short short8v;
typedef __attribute__((ext_vector_type(4))) float f32x4;

__device__ __forceinline__ unsigned short f2bf(float f) {
    unsigned int u = __float_as_uint(f);
    u += 0x7FFFu + ((u >> 16) & 1u);   // round-to-nearest-even
    return (unsigned short)(u >> 16);
}
__device__ __forceinline__ float bf2f(unsigned short s) {
    return __uint_as_float((unsigned int)s << 16);
}

// ---------------- CSR build ----------------
__global__ void k_count(const int* __restrict__ dst, int* __restrict__ cnt) {
    int e = blockIdx.x * blockDim.x + threadIdx.x;
    if (e < N_EDGES) atomicAdd(&cnt[dst[e]], 1);
}

// f32 -> bf16 bulk convert, both weight matrices in one launch
__global__ void k_tobf2(const float* __restrict__ w1, unsigned short* __restrict__ w1b, int n1_8,
                        const float* __restrict__ w2, unsigned short* __restrict__ w2b, int n2_8) {
    int t = blockIdx.x * blockDim.x + threadIdx.x;
    const float* p;
    unsigned short* o;
    if (t < n1_8) { p = w1 + (size_t)t * 8; o = w1b + (size_t)t * 8; }
    else if (t < n1_8 + n2_8) { int u = t - n1_8; p = w2 + (size_t)u * 8; o = w2b + (size_t)u * 8; }
    else return;
    float4 a = *(const float4*)p;
    float4 b = *(const float4*)(p + 4);
    unsigned int o0 = f2bf(a.x) | ((unsigned int)f2bf(a.y) << 16);
    unsigned int o1 = f2bf(a.z) | ((unsigned int)f2bf(a.w) << 16);
    unsigned int o2 = f2bf(b.x) | ((unsigned int)f2bf(b.y) << 16);
    unsigned int o3 = f2bf(b.z) | ((unsigned int)f2bf(b.w) << 16);
    *(uint4*)o = make_uint4(o0, o1, o2, o3);
}

// prescaled bf16 copy of x: xb[i][c] = bf16(x[i][c] * dinv[i])
__global__ void k_xtobf(const float* __restrict__ x, const float* __restrict__ dinv,
                        unsigned short* __restrict__ xb) {
    int t = blockIdx.x * blockDim.x + threadIdx.x;
    if (t >= N_NODES * (IN_F / 8)) return;
    int node = t / (IN_F / 8);
    float sc = dinv[node];
    const float* p = x + (size_t)t * 8;
    float4 a = *(const float4*)p;
    float4 b = *(const float4*)(p + 4);
    unsigned int o0 = f2bf(a.x * sc) | ((unsigned int)f2bf(a.y * sc) << 16);
    unsigned int o1 = f2bf(a.z * sc) | ((unsigned int)f2bf(a.w * sc) << 16);
    unsigned int o2 = f2bf(b.x * sc) | ((unsigned int)f2bf(b.y * sc) << 16);
    unsigned int o3 = f2bf(b.z * sc) | ((unsigned int)f2bf(b.w * sc) << 16);
    *(uint4*)(xb + (size_t)t * 8) = make_uint4(o0, o1, o2, o3);
}

// multi-block exclusive scan; also writes dinv = rsqrt(cnt+1)
__global__ void k_scan1(const int* __restrict__ cnt, int* __restrict__ rowptr,
                        int* __restrict__ bsum, float* __restrict__ dinv) {
    __shared__ int sm[SCAN_B];
    int t = threadIdx.x, base = blockIdx.x * SCAN_B;
    int v = (base + t < N_NODES) ? cnt[base + t] : 0;
    if (base + t < N_NODES) dinv[base + t] = rsqrtf((float)v + 1.0f);
    int x = v;
    sm[t] = x;
    __syncthreads();
    for (int off = 1; off < SCAN_B; off <<= 1) {
        int add = (t >= off) ? sm[t - off] : 0;
        __syncthreads();
        x += add;
        sm[t] = x;
        __syncthreads();
    }
    if (base + t < N_NODES) rowptr[base + t] = x - v;
    if (t == SCAN_B - 1) bsum[blockIdx.x] = x;
}

__global__ void k_scan2(int* __restrict__ bsum) {
    __shared__ int sm[128];
    int t = threadIdx.x;
    int v = (t < SCAN_NB) ? bsum[t] : 0;
    int x = v;
    sm[t] = x;
    __syncthreads();
    for (int off = 1; off < 128; off <<= 1) {
        int add = (t >= off) ? sm[t - off] : 0;
        __syncthreads();
        x += add;
        sm[t] = x;
        __syncthreads();
    }
    if (t < SCAN_NB) bsum[t] = x - v;
}

__global__ void k_scan3(int* __restrict__ rowptr, const int* __restrict__ bsum) {
    int i = blockIdx.x * blockDim.x + threadIdx.x;
    if (i < N_NODES) rowptr[i] += bsum[i >> 10];
}

__global__ void k_fill(const int* __restrict__ src, const int* __restrict__ dst,
                       const int* __restrict__ rowptr, int* __restrict__ fill,
                       int* __restrict__ col) {
    int e = blockIdx.x * blockDim.x + threadIdx.x;
    if (e >= N_EDGES) return;
    int d = dst[e];
    int p = rowptr[d] + atomicAdd(&fill[d], 1);
    col[p] = src[e];
}

// ---------------- aggregation, deep-MLP gather (R9 structure) ----------------
// out[i] = bf16( dinv[i] * (hb[i] + sum_j hb[j]) ), rows prescaled bf16.
template<int W, int U>
__global__ void __launch_bounds__(256)
k_aggv(const unsigned short* __restrict__ hb, const float* __restrict__ dinv,
       const int* __restrict__ rowptr, const int* __restrict__ cnt,
       const int* __restrict__ col, unsigned short* __restrict__ out) {
    constexpr int LR = W / 8;          // lanes per row (uint4 = 8 bf16/lane)
    constexpr int NW = 64 / LR;        // rows per wave per step
    int wid = threadIdx.x >> 6;
    int i = blockIdx.x * 4 + wid;
    if (i >= N_NODES) return;
    int lane = threadIdx.x & 63;
    int g = lane / LR;                 // neighbor slot within wave
    int s = lane % LR;                 // column slot (8 bf16)
    float dd = dinv[i];
    int beg = rowptr[i] - 1;           // virtual v: 0 -> self, v>=1 -> col[beg+v]
    int total = cnt[i] + 1;
    const unsigned short* hbs = hb + s * 8;
    float acc[8] = {};
    for (int v = 0; v < total; v += U * NW) {
        uint4 d[U];
        #pragma unroll
        for (int u = 0; u < U; ++u) {
            int idx = v + u * NW + g;
            d[u] = make_uint4(0u, 0u, 0u, 0u);
            if (idx < total) {
                int r = (idx == 0) ? i : col[beg + idx];
                d[u] = *(const uint4*)(hbs + (size_t)r * W);
            }
        }
        #pragma unroll
        for (int u = 0; u < U; ++u) {
            acc[0] += bf2f((unsigned short)(d[u].x & 0xffffu));
            acc[1] += bf2f((unsigned short)(d[u].x >> 16));
            acc[2] += bf2f((unsigned short)(d[u].y & 0xffffu));
            acc[3] += bf2f((unsigned short)(d[u].y >> 16));
            acc[4] += bf2f((unsigned short)(d[u].z & 0xffffu));
            acc[5] += bf2f((unsigned short)(d[u].z >> 16));
            acc[6] += bf2f((unsigned short)(d[u].w & 0xffffu));
            acc[7] += bf2f((unsigned short)(d[u].w >> 16));
        }
    }
    #pragma unroll
    for (int off = LR; off < 64; off <<= 1)
        #pragma unroll
        for (int c = 0; c < 8; ++c)
            acc[c] += __shfl_xor(acc[c], off, 64);
    if (g == 0) {
        unsigned int o0 = f2bf(dd * acc[0]) | ((unsigned int)f2bf(dd * acc[1]) << 16);
        unsigned int o1 = f2bf(dd * acc[2]) | ((unsigned int)f2bf(dd * acc[3]) << 16);
        unsigned int o2 = f2bf(dd * acc[4]) | ((unsigned int)f2bf(dd * acc[5]) << 16);
        unsigned int o3 = f2bf(dd * acc[6]) | ((unsigned int)f2bf(dd * acc[7]) << 16);
        *(uint4*)(out + (size_t)i * W + s * 8) = make_uint4(o0, o1, o2, o3);
    }
}

// ---------------- MFMA GEMM v2: 8 waves, reg-staged double buffer ----------------
// relu(A @ W^T + bias); A:[M,K] bf16, W:[256,K] bf16. BM=BN=128, BK=64.
// 512 threads = 8 waves (4x2); wave owns 32x64 via 2x4 16x16x32 frags.
// Tile t+1's global loads issue BEFORE tile t's MFMAs (latency hides under compute).
template<int K, bool FUSE>
__global__ void __launch_bounds__(512)
k_mgemm(const unsigned short* __restrict__ A, const unsigned short* __restrict__ Wb,
        const float* __restrict__ bias, unsigned short* __restrict__ Cb,
        const float* __restrict__ dinv, const int* __restrict__ batch,
        float* __restrict__ pooled) {
    constexpr int LDT = 72;   // padded row stride (shorts), 16B-aligned writes
    constexpr int NT = K / 64;
    __shared__ unsigned short Asl[128 * LDT];
    __shared__ unsigned short Bsl[128 * LDT];
    __shared__ float red[128];
    int row0 = blockIdx.x * 128;
    int col0 = blockIdx.y * 128;
    int t = threadIdx.x;
    int wid = t >> 6, lane = t & 63;
    int fr = lane & 15, fq = lane >> 4;
    int wr = wid >> 1, wc = wid & 1;   // wr 0..3 (32-row strip), wc 0..1 (64-col strip)

    f32x4 acc[2][4] = {};
    uint4 ra[2], rb[2];

    // prologue: load + store tile 0
    #pragma unroll
    for (int p = 0; p < 2; ++p) {
        int idx = p * 512 + t, r = idx >> 3, c8 = (idx & 7) * 8;
        int grow = row0 + r;
        ra[p] = make_uint4(0u, 0u, 0u, 0u);
        if (grow < N_NODES) ra[p] = *(const uint4*)(A + (size_t)grow * K + c8);
        rb[p] = *(const uint4*)(Wb + (size_t)(col0 + r) * K + c8);
    }
    #pragma unroll
    for (int p = 0; p < 2; ++p) {
        int idx = p * 512 + t, r = idx >> 3, c8 = (idx & 7) * 8;
        *(uint4*)(Asl + r * LDT + c8) = ra[p];
        *(uint4*)(Bsl + r * LDT + c8) = rb[p];
    }
    __syncthreads();

    for (int tt = 0; tt < NT; ++tt) {
        if (tt + 1 < NT) {
            int kc = (tt + 1) * 64;
            #pragma unroll
            for (int p = 0; p < 2; ++p) {
                int idx = p * 512 + t, r = idx >> 3, c8 = (idx & 7) * 8;
                int grow = row0 + r;
                ra[p] = make_uint4(0u, 0u, 0u, 0u);
                if (grow < N_NODES) ra[p] = *(const uint4*)(A + (size_t)grow * K + kc + c8);
                rb[p] = *(const uint4*)(Wb + (size_t)(col0 + r) * K + kc + c8);
            }
        }
        #pragma unroll
        for (int k0 = 0; k0 < 64; k0 += 32) {
            short8v af[2], bf[4];
            #pragma unroll
            for (int m = 0; m < 2; ++m)
                af[m] = *(const short8v*)(Asl + (wr * 32 + m * 16 + fr) * LDT + k0 + fq * 8);
            #pragma unroll
            for (int n = 0; n < 4; ++n)
                bf[n] = *(const short8v*)(Bsl + (wc * 64 + n * 16 + fr) * LDT + k0 + fq * 8);
            #pragma unroll
            for (int m = 0; m < 2; ++m)
                #pragma unroll
                for (int n = 0; n < 4; ++n)
                    acc[m][n] = __builtin_amdgcn_mfma_f32_16x16x32_bf16(af[m], bf[n], acc[m][n], 0, 0, 0);
        }
        __syncthreads();
        if (tt + 1 < NT) {
            #pragma unroll
            for (int p = 0; p < 2; ++p) {
                int idx = p * 512 + t, r = idx >> 3, c8 = (idx & 7) * 8;
                *(uint4*)(Asl + r * LDT + c8) = ra[p];
                *(uint4*)(Bsl + r * LDT + c8) = rb[p];
            }
            __syncthreads();
        }
    }

    float bv[4];
    #pragma unroll
    for (int n = 0; n < 4; ++n) bv[n] = bias[col0 + wc * 64 + n * 16 + fr];

    if (!FUSE) {
        #pragma unroll
        for (int m = 0; m < 2; ++m) {
            #pragma unroll
            for (int j = 0; j < 4; ++j) {
                int row = row0 + wr * 32 + m * 16 + fq * 4 + j;
                if (row >= N_NODES) continue;
                float sc = dinv[row];
                unsigned short* o = Cb + (size_t)row * HID + col0 + wc * 64;
                #pragma unroll
                for (int n = 0; n < 4; ++n) {
                    float v = fmaxf(acc[m][n][j] + bv[n], 0.f) * sc;
                    o[n * 16 + fr] = f2bf(v);
                }
            }
        }
    } else {
        int gm[2][4];
        #pragma unroll
        for (int m = 0; m < 2; ++m)
            #pragma unroll
            for (int j = 0; j < 4; ++j) {
                int row = row0 + wr * 32 + m * 16 + fq * 4 + j;
                gm[m][j] = (row < N_NODES) ? batch[row] : -1;
                #pragma unroll
                for (int n = 0; n < 4; ++n)
                    acc[m][n][j] = fmaxf(acc[m][n][j] + bv[n], 0.f);
            }
        int rhi = row0 + 127; if (rhi >= N_NODES) rhi = N_NODES - 1;
        int glo = batch[row0], ghi = batch[rhi];
        for (int g = glo; g <= ghi; ++g) {
            if (t < 128) red[t] = 0.f;
            __syncthreads();
            #pragma unroll
            for (int n = 0; n < 4; ++n) {
                float s = 0.f;
                #pragma unroll
                for (int m = 0; m < 2; ++m)
                    #pragma unroll
                    for (int j = 0; j < 4; ++j)
                        if (gm[m][j] == g) s += acc[m][n][j];
                if (s != 0.f) atomicAdd(&red[wc * 64 + n * 16 + fr], s);
            }
            __syncthreads();
            if (t < 128 && red[t] != 0.f)
                atomicAdd(&pooled[g * HID + col0 + t], red[t]);
            __syncthreads();
        }
    }
}

// ---------------- final FC (per-graph counts via inline binary search) ----------------
__global__ void k_final(const float* __restrict__ pooled, const int* __restrict__ batch,
                        const float* __restrict__ Wfc, const float* __restrict__ bfc,
                        float* __restrict__ out) {
    int t = blockIdx.x * blockDim.x + threadIdx.x;
    if (t >= N_GRAPHS * OUT_F) return;
    int g = t / OUT_F, o = t % OUT_F;
    int lo = 0, hi = N_NODES;
    while (lo < hi) { int mid = (lo + hi) >> 1; if (batch[mid] < g) lo = mid + 1; else hi = mid; }
    int a = lo;
    lo = 0; hi = N_NODES;
    while (lo < hi) { int mid = (lo + hi) >> 1; if (batch[mid] < g + 1) lo = mid + 1; else hi = mid; }
    float inv = 1.0f / fmaxf((float)(lo - a), 1.0f);
    float s = 0.f;
    for (int k = 0; k < HID; ++k) s += pooled[g * HID + k] * Wfc[o * HID + k];
    out[t] = s * inv + bfc[o];
}

extern "C" void kernel_launch(void* const* d_in, const int* in_sizes, int n_in,
                              void* d_out, int out_size, void* d_ws, size_t ws_size,
                              hipStream_t stream) {
    const float* x    = (const float*)d_in[0];
    const int*   ei   = (const int*)d_in[1];
    const int*   bat  = (const int*)d_in[2];
    const float* W1   = (const float*)d_in[3];
    const float* b1   = (const float*)d_in[4];
    const float* W2   = (const float*)d_in[5];
    const float* b2   = (const float*)d_in[6];
    const float* Wfc  = (const float*)d_in[7];
    const float* bfc  = (const float*)d_in[8];
    float* out = (float*)d_out;

    const int* src = ei;
    const int* dst = ei + N_EDGES;

    float* ws = (float*)d_ws;
    float* dinv    = ws + 0;                 // 100096
    float* pooled  = ws + 100096;            // 16384
    int*   cnt     = (int*)(ws + 116608);    // 100096
    int*   rowptr  = (int*)(ws + 216704);    // 100224
    int*   fill    = (int*)(ws + 316928);    // 100000
    int*   bsum    = (int*)(ws + 416928);    // 128
    int*   col     = (int*)(ws + 417056);    // 1600000
    unsigned short* W1b = (unsigned short*)(ws + 2017056);   // 32768 bf16
    unsigned short* W2b = (unsigned short*)(ws + 2033440);   // 65536 bf16
    unsigned short* xb  = (unsigned short*)(ws + 2066208);   // 100000*128 bf16
    unsigned short* h1b = (unsigned short*)(ws + 8466208);   // 100000*256 bf16
    unsigned short* aggb = (unsigned short*)(ws + 21266208); // up to 100000*256 bf16

    const int B = 256;

    // single contiguous zero: pooled .. bsum (excludes col)
    hipMemsetAsync(pooled, 0, (size_t)(417056 - 100096) * 4, stream);

    k_count<<<(N_EDGES + B - 1) / B, B, 0, stream>>>(dst, cnt);
    k_scan1<<<SCAN_NB, SCAN_B, 0, stream>>>(cnt, rowptr, bsum, dinv);
    k_scan2<<<1, 128, 0, stream>>>(bsum);
    k_scan3<<<(N_NODES + B - 1) / B, B, 0, stream>>>(rowptr, bsum);
    k_tobf2<<<((HID * IN_F + HID * HID) / 8 + B - 1) / B, B, 0, stream>>>(
        W1, W1b, HID * IN_F / 8, W2, W2b, HID * HID / 8);
    k_xtobf<<<(N_NODES * (IN_F / 8) + B - 1) / B, B, 0, stream>>>(x, dinv, xb);
    k_fill<<<(N_EDGES + B - 1) / B, B, 0, stream>>>(src, dst, rowptr, fill, col);

    // layer 1: aggb = bf16(A_hat @ x), h1b = bf16(relu(aggb@W1^T+b1)*dinv)
    k_aggv<IN_F, 4><<<(N_NODES + 3) / 4, 256, 0, stream>>>(xb, dinv, rowptr, cnt, col, aggb);
    {
        dim3 grid((N_NODES + 127) / 128, HID / 128);
        k_mgemm<IN_F, false><<<grid, 512, 0, stream>>>(aggb, W1b, b1, h1b, dinv, nullptr, nullptr);
    }

    // layer 2: aggb = bf16(A_hat @ h1), pooled += relu(aggb@W2^T+b2) segment-reduced
    k_aggv<HID, 4><<<(N_NODES + 3) / 4, 256, 0, stream>>>(h1b, dinv, rowptr, cnt, col, aggb);
    {
        dim3 grid((N_NODES + 127) / 128, HID / 128);
        k_mgemm<HID, true><<<grid, 512, 0, stream>>>(aggb, W2b, b2, nullptr, nullptr, bat, pooled);
    }

    k_final<<<(N_GRAPHS * OUT_F + B - 1) / B, B, 0, stream>>>(pooled, bat, Wfc, bfc, out);
}

// Round 12
// 470.814 us; speedup vs baseline: 1.1584x; 1.0214x over previous
//
#include <hip/hip_runtime.h>

#define N_NODES 100000
#define N_EDGES 1600000
#define N_GRAPHS 64
#define IN_F 128
#define HID 256
#define OUT_F 10

#define SCAN_B 1024
#define SCAN_NB ((N_NODES + SCAN_B - 1) / SCAN_B)   // 98
#define NX8 (N_NODES * (IN_F / 8))                  // x-convert work items

typedef __attribute__((ext_vector_type(8))) short short8v;
typedef __attribute__((ext_vector_type(4))) float f32x4;

__device__ __forceinline__ unsigned short f2bf(float f) {
    unsigned int u = __float_as_uint(f);
    u += 0x7FFFu + ((u >> 16) & 1u);   // round-to-nearest-even
    return (unsigned short)(u >> 16);
}
__device__ __forceinline__ float bf2f(unsigned short s) {
    return __uint_as_float((unsigned int)s << 16);
}

// ---------------- CSR build ----------------
__global__ void k_count(const int* __restrict__ dst, int* __restrict__ cnt) {
    int e = blockIdx.x * blockDim.x + threadIdx.x;
    if (e < N_EDGES) atomicAdd(&cnt[dst[e]], 1);
}

// fused bf16 conversion: x (prescaled by dinv) + W1 + W2 in one launch
__global__ void k_cvt(const float* __restrict__ x, const float* __restrict__ dinv,
                      unsigned short* __restrict__ xb,
                      const float* __restrict__ w1, unsigned short* __restrict__ w1b,
                      const float* __restrict__ w2, unsigned short* __restrict__ w2b) {
    int t = blockIdx.x * blockDim.x + threadIdx.x;
    const float* p;
    unsigned short* o;
    float sc = 1.0f;
    if (t < NX8) {
        int node = t / (IN_F / 8);
        sc = dinv[node];
        p = x + (size_t)t * 8; o = xb + (size_t)t * 8;
    } else if (t < NX8 + HID * IN_F / 8) {
        int u = t - NX8;
        p = w1 + (size_t)u * 8; o = w1b + (size_t)u * 8;
    } else if (t < NX8 + HID * IN_F / 8 + HID * HID / 8) {
        int u = t - NX8 - HID * IN_F / 8;
        p = w2 + (size_t)u * 8; o = w2b + (size_t)u * 8;
    } else return;
    float4 a = *(const float4*)p;
    float4 b = *(const float4*)(p + 4);
    unsigned int o0 = f2bf(a.x * sc) | ((unsigned int)f2bf(a.y * sc) << 16);
    unsigned int o1 = f2bf(a.z * sc) | ((unsigned int)f2bf(a.w * sc) << 16);
    unsigned int o2 = f2bf(b.x * sc) | ((unsigned int)f2bf(b.y * sc) << 16);
    unsigned int o3 = f2bf(b.z * sc) | ((unsigned int)f2bf(b.w * sc) << 16);
    *(uint4*)o = make_uint4(o0, o1, o2, o3);
}

// multi-block exclusive scan stage 1; also writes dinv = rsqrt(cnt+1)
__global__ void k_scan1(const int* __restrict__ cnt, int* __restrict__ rowptr,
                        int* __restrict__ bsum, float* __restrict__ dinv) {
    __shared__ int sm[SCAN_B];
    int t = threadIdx.x, base = blockIdx.x * SCAN_B;
    int v = (base + t < N_NODES) ? cnt[base + t] : 0;
    if (base + t < N_NODES) dinv[base + t] = rsqrtf((float)v + 1.0f);
    int x = v;
    sm[t] = x;
    __syncthreads();
    for (int off = 1; off < SCAN_B; off <<= 1) {
        int add = (t >= off) ? sm[t - off] : 0;
        __syncthreads();
        x += add;
        sm[t] = x;
        __syncthreads();
    }
    if (base + t < N_NODES) rowptr[base + t] = x - v;
    if (t == SCAN_B - 1) bsum[blockIdx.x] = x;
}

// stage 2+3 fused: each block scans the 98 block sums in LDS, then offsets rowptr
__global__ void k_scan23(int* __restrict__ rowptr, const int* __restrict__ bsum) {
    __shared__ int sm[128];
    int t = threadIdx.x;
    if (t < 128) sm[t] = (t < SCAN_NB) ? bsum[t] : 0;
    __syncthreads();
    for (int off = 1; off < 128; off <<= 1) {
        int add = (t >= off && t < 128) ? sm[t - off] : 0;
        __syncthreads();
        if (t < 128) sm[t] += add;
        __syncthreads();
    }
    int i = blockIdx.x * blockDim.x + t;
    if (i < N_NODES) {
        int c = i >> 10;
        int pre = (c == 0) ? 0 : sm[c - 1];   // exclusive offset from inclusive scan
        rowptr[i] += pre;
    }
}

__global__ void k_fill(const int* __restrict__ src, const int* __restrict__ dst,
                       const int* __restrict__ rowptr, int* __restrict__ fill,
                       int* __restrict__ col) {
    int e = blockIdx.x * blockDim.x + threadIdx.x;
    if (e >= N_EDGES) return;
    int d = dst[e];
    int p = rowptr[d] + atomicAdd(&fill[d], 1);
    __builtin_nontemporal_store(src[e], &col[p]);
}

// ---------------- aggregation, deep-MLP gather, de-predicated main loop ----------------
// out[i] = bf16( dinv[i] * (hb[i] + sum_j hb[j]) ), rows prescaled bf16.
template<int W, int U>
__global__ void __launch_bounds__(256)
k_aggv(const unsigned short* __restrict__ hb, const float* __restrict__ dinv,
       const int* __restrict__ rowptr, const int* __restrict__ cnt,
       const int* __restrict__ col, unsigned short* __restrict__ out) {
    constexpr int LR = W / 8;          // lanes per row (uint4 = 8 bf16/lane)
    constexpr int NW = 64 / LR;        // rows per wave per step
    constexpr int STEP = U * NW;
    int wid = threadIdx.x >> 6;
    int i = blockIdx.x * 4 + wid;
    if (i >= N_NODES) return;
    int lane = threadIdx.x & 63;
    int g = lane / LR;                 // neighbor slot within wave
    int s = lane % LR;                 // column slot (8 bf16)
    float dd = dinv[i];
    int beg = rowptr[i] - 1;           // virtual v: 0 -> self, v>=1 -> col[beg+v]
    int total = cnt[i] + 1;
    const unsigned short* hbs = hb + s * 8;
    float acc[8] = {};

    #define ACCUM(dv)                                            \
        acc[0] += bf2f((unsigned short)((dv).x & 0xffffu));      \
        acc[1] += bf2f((unsigned short)((dv).x >> 16));          \
        acc[2] += bf2f((unsigned short)((dv).y & 0xffffu));      \
        acc[3] += bf2f((unsigned short)((dv).y >> 16));          \
        acc[4] += bf2f((unsigned short)((dv).z & 0xffffu));      \
        acc[5] += bf2f((unsigned short)((dv).z >> 16));          \
        acc[6] += bf2f((unsigned short)((dv).w & 0xffffu));      \
        acc[7] += bf2f((unsigned short)((dv).w >> 16));

    // step 0: contains self (idx==0) + bounds predication
    {
        uint4 d[U];
        #pragma unroll
        for (int u = 0; u < U; ++u) {
            int idx = u * NW + g;
            d[u] = make_uint4(0u, 0u, 0u, 0u);
            if (idx < total) {
                int r = (idx == 0) ? i : col[beg + idx];
                d[u] = *(const uint4*)(hbs + (size_t)r * W);
            }
        }
        #pragma unroll
        for (int u = 0; u < U; ++u) { ACCUM(d[u]) }
    }
    // full steps: no bounds check, no self check
    int v = STEP;
    for (; v + STEP <= total; v += STEP) {
        uint4 d[U];
        #pragma unroll
        for (int u = 0; u < U; ++u) {
            int r = col[beg + v + u * NW + g];
            d[u] = *(const uint4*)(hbs + (size_t)r * W);
        }
        #pragma unroll
        for (int u = 0; u < U; ++u) { ACCUM(d[u]) }
    }
    // tail step
    if (v < total) {
        uint4 d[U];
        #pragma unroll
        for (int u = 0; u < U; ++u) {
            int idx = v + u * NW + g;
            d[u] = make_uint4(0u, 0u, 0u, 0u);
            if (idx < total) {
                int r = col[beg + idx];
                d[u] = *(const uint4*)(hbs + (size_t)r * W);
            }
        }
        #pragma unroll
        for (int u = 0; u < U; ++u) { ACCUM(d[u]) }
    }
    #undef ACCUM

    #pragma unroll
    for (int off = LR; off < 64; off <<= 1)
        #pragma unroll
        for (int c = 0; c < 8; ++c)
            acc[c] += __shfl_xor(acc[c], off, 64);
    if (g == 0) {
        unsigned int o0 = f2bf(dd * acc[0]) | ((unsigned int)f2bf(dd * acc[1]) << 16);
        unsigned int o1 = f2bf(dd * acc[2]) | ((unsigned int)f2bf(dd * acc[3]) << 16);
        unsigned int o2 = f2bf(dd * acc[4]) | ((unsigned int)f2bf(dd * acc[5]) << 16);
        unsigned int o3 = f2bf(dd * acc[6]) | ((unsigned int)f2bf(dd * acc[7]) << 16);
        *(uint4*)(out + (size_t)i * W + s * 8) = make_uint4(o0, o1, o2, o3);
    }
}

// ---------------- MFMA GEMM (R9 4-wave version): relu(A @ W^T + bias) ----------------
// BM=128, BN=128, BK=64, 256 threads = 4 waves (2x2), each wave 64x64 via 4x4 16x16x32 frags.
template<int K, bool FUSE>
__global__ void __launch_bounds__(256)
k_mgemm(const unsigned short* __restrict__ A, const unsigned short* __restrict__ Wb,
        const float* __restrict__ bias, unsigned short* __restrict__ Cb,
        const float* __restrict__ dinv, const int* __restrict__ batch,
        float* __restrict__ pooled) {
    constexpr int LDT = 72;   // padded row stride (shorts)
    __shared__ unsigned short Asl[128 * LDT];
    __shared__ unsigned short Bsl[128 * LDT];
    __shared__ float red[128];
    int row0 = blockIdx.x * 128;
    int col0 = blockIdx.y * 128;
    int t = threadIdx.x;
    int wid = t >> 6, lane = t & 63;
    int fr = lane & 15, fq = lane >> 4;
    int wr = wid >> 1, wc = wid & 1;

    f32x4 acc[4][4] = {};

    for (int kc = 0; kc < K; kc += 64) {
        #pragma unroll
        for (int p = 0; p < 4; ++p) {
            int idx = p * 256 + t;            // 0..1023
            int r = idx >> 3;                 // 0..127
            int c8 = (idx & 7) * 8;           // bf16 col
            uint4 v = make_uint4(0u, 0u, 0u, 0u);
            int grow = row0 + r;
            if (grow < N_NODES) v = *(const uint4*)(A + (size_t)grow * K + kc + c8);
            *(uint4*)(Asl + r * LDT + c8) = v;
            uint4 w = *(const uint4*)(Wb + (size_t)(col0 + r) * K + kc + c8);
            *(uint4*)(Bsl + r * LDT + c8) = w;
        }
        __syncthreads();
        #pragma unroll
        for (int k0 = 0; k0 < 64; k0 += 32) {
            short8v af[4], bf[4];
            #pragma unroll
            for (int m = 0; m < 4; ++m)
                af[m] = *(const short8v*)(Asl + (wr * 64 + m * 16 + fr) * LDT + k0 + fq * 8);
            #pragma unroll
            for (int n = 0; n < 4; ++n)
                bf[n] = *(const short8v*)(Bsl + (wc * 64 + n * 16 + fr) * LDT + k0 + fq * 8);
            #pragma unroll
            for (int m = 0; m < 4; ++m)
                #pragma unroll
                for (int n = 0; n < 4; ++n)
                    acc[m][n] = __builtin_amdgcn_mfma_f32_16x16x32_bf16(af[m], bf[n], acc[m][n], 0, 0, 0);
        }
        __syncthreads();
    }

    float bv[4];
    #pragma unroll
    for (int n = 0; n < 4; ++n) bv[n] = bias[col0 + wc * 64 + n * 16 + fr];

    if (!FUSE) {
        #pragma unroll
        for (int m = 0; m < 4; ++m) {
            #pragma unroll
            for (int j = 0; j < 4; ++j) {
                int row = row0 + wr * 64 + m * 16 + fq * 4 + j;
                if (row >= N_NODES) continue;
                float sc = dinv[row];
                unsigned short* o = Cb + (size_t)row * HID + col0 + wc * 64;
                #pragma unroll
                for (int n = 0; n < 4; ++n) {
                    float v = fmaxf(acc[m][n][j] + bv[n], 0.f) * sc;
                    o[n * 16 + fr] = f2bf(v);
                }
            }
        }
    } else {
        int gm[4][4];
        #pragma unroll
        for (int m = 0; m < 4; ++m)
            #pragma unroll
            for (int j = 0; j < 4; ++j) {
                int row = row0 + wr * 64 + m * 16 + fq * 4 + j;
                gm[m][j] = (row < N_NODES) ? batch[row] : -1;
                #pragma unroll
                for (int n = 0; n < 4; ++n)
                    acc[m][n][j] = fmaxf(acc[m][n][j] + bv[n], 0.f);
            }
        int rhi = row0 + 127; if (rhi >= N_NODES) rhi = N_NODES - 1;
        int glo = batch[row0], ghi = batch[rhi];
        for (int g = glo; g <= ghi; ++g) {
            if (t < 128) red[t] = 0.f;
            __syncthreads();
            #pragma unroll
            for (int n = 0; n < 4; ++n) {
                float s = 0.f;
                #pragma unroll
                for (int m = 0; m < 4; ++m)
                    #pragma unroll
                    for (int j = 0; j < 4; ++j)
                        if (gm[m][j] == g) s += acc[m][n][j];
                if (s != 0.f) atomicAdd(&red[wc * 64 + n * 16 + fr], s);
            }
            __syncthreads();
            if (t < 128 && red[t] != 0.f)
                atomicAdd(&pooled[g * HID + col0 + t], red[t]);
            __syncthreads();
        }
    }
}

// ---------------- final FC (per-graph counts via inline binary search) ----------------
__global__ void k_final(const float* __restrict__ pooled, const int* __restrict__ batch,
                        const float* __restrict__ Wfc, const float* __restrict__ bfc,
                        float* __restrict__ out) {
    int t = blockIdx.x * blockDim.x + threadIdx.x;
    if (t >= N_GRAPHS * OUT_F) return;
    int g = t / OUT_F, o = t % OUT_F;
    int lo = 0, hi = N_NODES;
    while (lo < hi) { int mid = (lo + hi) >> 1; if (batch[mid] < g) lo = mid + 1; else hi = mid; }
    int a = lo;
    lo = 0; hi = N_NODES;
    while (lo < hi) { int mid = (lo + hi) >> 1; if (batch[mid] < g + 1) lo = mid + 1; else hi = mid; }
    float inv = 1.0f / fmaxf((float)(lo - a), 1.0f);
    float s = 0.f;
    for (int k = 0; k < HID; ++k) s += pooled[g * HID + k] * Wfc[o * HID + k];
    out[t] = s * inv + bfc[o];
}

extern "C" void kernel_launch(void* const* d_in, const int* in_sizes, int n_in,
                              void* d_out, int out_size, void* d_ws, size_t ws_size,
                              hipStream_t stream) {
    const float* x    = (const float*)d_in[0];
    const int*   ei   = (const int*)d_in[1];
    const int*   bat  = (const int*)d_in[2];
    const float* W1   = (const float*)d_in[3];
    const float* b1   = (const float*)d_in[4];
    const float* W2   = (const float*)d_in[5];
    const float* b2   = (const float*)d_in[6];
    const float* Wfc  = (const float*)d_in[7];
    const float* bfc  = (const float*)d_in[8];
    float* out = (float*)d_out;

    const int* src = ei;
    const int* dst = ei + N_EDGES;

    float* ws = (float*)d_ws;
    float* dinv    = ws + 0;                 // 100096
    float* pooled  = ws + 100096;            // 16384
    int*   cnt     = (int*)(ws + 116608);    // 100096
    int*   rowptr  = (int*)(ws + 216704);    // 100224
    int*   fill    = (int*)(ws + 316928);    // 100000
    int*   bsum    = (int*)(ws + 416928);    // 128
    int*   col     = (int*)(ws + 417056);    // 1600000
    unsigned short* W1b = (unsigned short*)(ws + 2017056);   // 32768 bf16
    unsigned short* W2b = (unsigned short*)(ws + 2033440);   // 65536 bf16
    unsigned short* xb  = (unsigned short*)(ws + 2066208);   // 100000*128 bf16
    unsigned short* h1b = (unsigned short*)(ws + 8466208);   // 100000*256 bf16
    unsigned short* aggb = (unsigned short*)(ws + 21266208); // up to 100000*256 bf16

    const int B = 256;

    // single contiguous zero: pooled .. bsum (excludes col)
    hipMemsetAsync(pooled, 0, (size_t)(417056 - 100096) * 4, stream);

    k_count<<<(N_EDGES + B - 1) / B, B, 0, stream>>>(dst, cnt);
    k_scan1<<<SCAN_NB, SCAN_B, 0, stream>>>(cnt, rowptr, bsum, dinv);
    k_scan23<<<(N_NODES + B - 1) / B, B, 0, stream>>>(rowptr, bsum);
    {
        int tot = NX8 + HID * IN_F / 8 + HID * HID / 8;
        k_cvt<<<(tot + B - 1) / B, B, 0, stream>>>(x, dinv, xb, W1, W1b, W2, W2b);
    }
    k_fill<<<(N_EDGES + B - 1) / B, B, 0, stream>>>(src, dst, rowptr, fill, col);

    // layer 1: aggb = bf16(A_hat @ x), h1b = bf16(relu(aggb@W1^T+b1)*dinv)
    k_aggv<IN_F, 4><<<(N_NODES + 3) / 4, 256, 0, stream>>>(xb, dinv, rowptr, cnt, col, aggb);
    {
        dim3 grid((N_NODES + 127) / 128, HID / 128);
        k_mgemm<IN_F, false><<<grid, 256, 0, stream>>>(aggb, W1b, b1, h1b, dinv, nullptr, nullptr);
    }

    // layer 2: aggb = bf16(A_hat @ h1), pooled += relu(aggb@W2^T+b2) segment-reduced
    k_aggv<HID, 4><<<(N_NODES + 3) / 4, 256, 0, stream>>>(h1b, dinv, rowptr, cnt, col, aggb);
    {
        dim3 grid((N_NODES + 127) / 128, HID / 128);
        k_mgemm<HID, true><<<grid, 256, 0, stream>>>(aggb, W2b, b2, nullptr, nullptr, bat, pooled);
    }

    k_final<<<(N_GRAPHS * OUT_F + B - 1) / B, B, 0, stream>>>(pooled, bat, Wfc, bfc, out);
}

// Round 13
// 420.856 us; speedup vs baseline: 1.2959x; 1.1187x over previous
//
#include <hip/hip_runtime.h>

#define N_NODES 100000
#define N_EDGES 1600000
#define N_GRAPHS 64
#define IN_F 128
#define HID 256
#define OUT_F 10

#define SCAN_B 1024
#define SCAN_NB ((N_NODES + SCAN_B - 1) / SCAN_B)   // 98
#define NX8 (N_NODES * (IN_F / 8))                  // x-convert work items

typedef __attribute__((ext_vector_type(8))) short short8v;
typedef __attribute__((ext_vector_type(4))) float f32x4;

__device__ __forceinline__ unsigned short f2bf(float f) {
    unsigned int u = __float_as_uint(f);
    u += 0x7FFFu + ((u >> 16) & 1u);   // round-to-nearest-even
    return (unsigned short)(u >> 16);
}
__device__ __forceinline__ float bf2f(unsigned short s) {
    return __uint_as_float((unsigned int)s << 16);
}

// ---------------- CSR build ----------------
// counting pass also captures each edge's slot within its dst bin (free: the
// atomicAdd return value), so the fill pass needs NO atomics.
__global__ void k_countp(const int* __restrict__ dst, int* __restrict__ cnt,
                         int* __restrict__ plocal) {
    int e = blockIdx.x * blockDim.x + threadIdx.x;
    if (e < N_EDGES) plocal[e] = atomicAdd(&cnt[dst[e]], 1);
}

// atomic-free scatter: col[rowptr[dst] + plocal] = src
__global__ void k_fill2(const int* __restrict__ src, const int* __restrict__ dst,
                        const int* __restrict__ rowptr, const int* __restrict__ plocal,
                        int* __restrict__ col) {
    int e = blockIdx.x * blockDim.x + threadIdx.x;
    if (e >= N_EDGES) return;
    int p = rowptr[dst[e]] + plocal[e];
    __builtin_nontemporal_store(src[e], &col[p]);
}

// fused bf16 conversion: x (prescaled by dinv) + W1 + W2 in one launch
__global__ void k_cvt(const float* __restrict__ x, const float* __restrict__ dinv,
                      unsigned short* __restrict__ xb,
                      const float* __restrict__ w1, unsigned short* __restrict__ w1b,
                      const float* __restrict__ w2, unsigned short* __restrict__ w2b) {
    int t = blockIdx.x * blockDim.x + threadIdx.x;
    const float* p;
    unsigned short* o;
    float sc = 1.0f;
    if (t < NX8) {
        int node = t / (IN_F / 8);
        sc = dinv[node];
        p = x + (size_t)t * 8; o = xb + (size_t)t * 8;
    } else if (t < NX8 + HID * IN_F / 8) {
        int u = t - NX8;
        p = w1 + (size_t)u * 8; o = w1b + (size_t)u * 8;
    } else if (t < NX8 + HID * IN_F / 8 + HID * HID / 8) {
        int u = t - NX8 - HID * IN_F / 8;
        p = w2 + (size_t)u * 8; o = w2b + (size_t)u * 8;
    } else return;
    float4 a = *(const float4*)p;
    float4 b = *(const float4*)(p + 4);
    unsigned int o0 = f2bf(a.x * sc) | ((unsigned int)f2bf(a.y * sc) << 16);
    unsigned int o1 = f2bf(a.z * sc) | ((unsigned int)f2bf(a.w * sc) << 16);
    unsigned int o2 = f2bf(b.x * sc) | ((unsigned int)f2bf(b.y * sc) << 16);
    unsigned int o3 = f2bf(b.z * sc) | ((unsigned int)f2bf(b.w * sc) << 16);
    *(uint4*)o = make_uint4(o0, o1, o2, o3);
}

// multi-block exclusive scan stage 1; also writes dinv = rsqrt(cnt+1)
__global__ void k_scan1(const int* __restrict__ cnt, int* __restrict__ rowptr,
                        int* __restrict__ bsum, float* __restrict__ dinv) {
    __shared__ int sm[SCAN_B];
    int t = threadIdx.x, base = blockIdx.x * SCAN_B;
    int v = (base + t < N_NODES) ? cnt[base + t] : 0;
    if (base + t < N_NODES) dinv[base + t] = rsqrtf((float)v + 1.0f);
    int x = v;
    sm[t] = x;
    __syncthreads();
    for (int off = 1; off < SCAN_B; off <<= 1) {
        int add = (t >= off) ? sm[t - off] : 0;
        __syncthreads();
        x += add;
        sm[t] = x;
        __syncthreads();
    }
    if (base + t < N_NODES) rowptr[base + t] = x - v;
    if (t == SCAN_B - 1) bsum[blockIdx.x] = x;
}

// stage 2+3 fused: each block scans the 98 block sums in LDS, then offsets rowptr
__global__ void k_scan23(int* __restrict__ rowptr, const int* __restrict__ bsum) {
    __shared__ int sm[128];
    int t = threadIdx.x;
    if (t < 128) sm[t] = (t < SCAN_NB) ? bsum[t] : 0;
    __syncthreads();
    for (int off = 1; off < 128; off <<= 1) {
        int add = (t >= off && t < 128) ? sm[t - off] : 0;
        __syncthreads();
        if (t < 128) sm[t] += add;
        __syncthreads();
    }
    int i = blockIdx.x * blockDim.x + t;
    if (i < N_NODES) {
        int c = i >> 10;
        int pre = (c == 0) ? 0 : sm[c - 1];   // exclusive offset from inclusive scan
        rowptr[i] += pre;
    }
}

// ---------------- aggregation, deep-MLP gather, de-predicated main loop ----------------
// out[i] = bf16( dinv[i] * (hb[i] + sum_j hb[j]) ), rows prescaled bf16.
template<int W, int U>
__global__ void __launch_bounds__(256)
k_aggv(const unsigned short* __restrict__ hb, const float* __restrict__ dinv,
       const int* __restrict__ rowptr, const int* __restrict__ cnt,
       const int* __restrict__ col, unsigned short* __restrict__ out) {
    constexpr int LR = W / 8;          // lanes per row (uint4 = 8 bf16/lane)
    constexpr int NW = 64 / LR;        // rows per wave per step
    constexpr int STEP = U * NW;
    int wid = threadIdx.x >> 6;
    int i = blockIdx.x * 4 + wid;
    if (i >= N_NODES) return;
    int lane = threadIdx.x & 63;
    int g = lane / LR;                 // neighbor slot within wave
    int s = lane % LR;                 // column slot (8 bf16)
    float dd = dinv[i];
    int beg = rowptr[i] - 1;           // virtual v: 0 -> self, v>=1 -> col[beg+v]
    int total = cnt[i] + 1;
    const unsigned short* hbs = hb + s * 8;
    float acc[8] = {};

    #define ACCUM(dv)                                            \
        acc[0] += bf2f((unsigned short)((dv).x & 0xffffu));      \
        acc[1] += bf2f((unsigned short)((dv).x >> 16));          \
        acc[2] += bf2f((unsigned short)((dv).y & 0xffffu));      \
        acc[3] += bf2f((unsigned short)((dv).y >> 16));          \
        acc[4] += bf2f((unsigned short)((dv).z & 0xffffu));      \
        acc[5] += bf2f((unsigned short)((dv).z >> 16));          \
        acc[6] += bf2f((unsigned short)((dv).w & 0xffffu));      \
        acc[7] += bf2f((unsigned short)((dv).w >> 16));

    // step 0: contains self (idx==0) + bounds predication
    {
        uint4 d[U];
        #pragma unroll
        for (int u = 0; u < U; ++u) {
            int idx = u * NW + g;
            d[u] = make_uint4(0u, 0u, 0u, 0u);
            if (idx < total) {
                int r = (idx == 0) ? i : col[beg + idx];
                d[u] = *(const uint4*)(hbs + (size_t)r * W);
            }
        }
        #pragma unroll
        for (int u = 0; u < U; ++u) { ACCUM(d[u]) }
    }
    // full steps: no bounds check, no self check
    int v = STEP;
    for (; v + STEP <= total; v += STEP) {
        uint4 d[U];
        #pragma unroll
        for (int u = 0; u < U; ++u) {
            int r = col[beg + v + u * NW + g];
            d[u] = *(const uint4*)(hbs + (size_t)r * W);
        }
        #pragma unroll
        for (int u = 0; u < U; ++u) { ACCUM(d[u]) }
    }
    // tail step
    if (v < total) {
        uint4 d[U];
        #pragma unroll
        for (int u = 0; u < U; ++u) {
            int idx = v + u * NW + g;
            d[u] = make_uint4(0u, 0u, 0u, 0u);
            if (idx < total) {
                int r = col[beg + idx];
                d[u] = *(const uint4*)(hbs + (size_t)r * W);
            }
        }
        #pragma unroll
        for (int u = 0; u < U; ++u) { ACCUM(d[u]) }
    }
    #undef ACCUM

    #pragma unroll
    for (int off = LR; off < 64; off <<= 1)
        #pragma unroll
        for (int c = 0; c < 8; ++c)
            acc[c] += __shfl_xor(acc[c], off, 64);
    if (g == 0) {
        unsigned int o0 = f2bf(dd * acc[0]) | ((unsigned int)f2bf(dd * acc[1]) << 16);
        unsigned int o1 = f2bf(dd * acc[2]) | ((unsigned int)f2bf(dd * acc[3]) << 16);
        unsigned int o2 = f2bf(dd * acc[4]) | ((unsigned int)f2bf(dd * acc[5]) << 16);
        unsigned int o3 = f2bf(dd * acc[6]) | ((unsigned int)f2bf(dd * acc[7]) << 16);
        *(uint4*)(out + (size_t)i * W + s * 8) = make_uint4(o0, o1, o2, o3);
    }
}

// ---------------- MFMA GEMM (4-wave): relu(A @ W^T + bias) ----------------
// BM=128, BN=128, BK=64, 256 threads = 4 waves (2x2), each wave 64x64 via 4x4 16x16x32 frags.
template<int K, bool FUSE>
__global__ void __launch_bounds__(256)
k_mgemm(const unsigned short* __restrict__ A, const unsigned short* __restrict__ Wb,
        const float* __restrict__ bias, unsigned short* __restrict__ Cb,
        const float* __restrict__ dinv, const int* __restrict__ batch,
        float* __restrict__ pooled) {
    constexpr int LDT = 72;   // padded row stride (shorts)
    __shared__ unsigned short Asl[128 * LDT];
    __shared__ unsigned short Bsl[128 * LDT];
    __shared__ float red[128];
    int row0 = blockIdx.x * 128;
    int col0 = blockIdx.y * 128;
    int t = threadIdx.x;
    int wid = t >> 6, lane = t & 63;
    int fr = lane & 15, fq = lane >> 4;
    int wr = wid >> 1, wc = wid & 1;

    f32x4 acc[4][4] = {};

    for (int kc = 0; kc < K; kc += 64) {
        #pragma unroll
        for (int p = 0; p < 4; ++p) {
            int idx = p * 256 + t;            // 0..1023
            int r = idx >> 3;                 // 0..127
            int c8 = (idx & 7) * 8;           // bf16 col
            uint4 v = make_uint4(0u, 0u, 0u, 0u);
            int grow = row0 + r;
            if (grow < N_NODES) v = *(const uint4*)(A + (size_t)grow * K + kc + c8);
            *(uint4*)(Asl + r * LDT + c8) = v;
            uint4 w = *(const uint4*)(Wb + (size_t)(col0 + r) * K + kc + c8);
            *(uint4*)(Bsl + r * LDT + c8) = w;
        }
        __syncthreads();
        #pragma unroll
        for (int k0 = 0; k0 < 64; k0 += 32) {
            short8v af[4], bf[4];
            #pragma unroll
            for (int m = 0; m < 4; ++m)
                af[m] = *(const short8v*)(Asl + (wr * 64 + m * 16 + fr) * LDT + k0 + fq * 8);
            #pragma unroll
            for (int n = 0; n < 4; ++n)
                bf[n] = *(const short8v*)(Bsl + (wc * 64 + n * 16 + fr) * LDT + k0 + fq * 8);
            #pragma unroll
            for (int m = 0; m < 4; ++m)
                #pragma unroll
                for (int n = 0; n < 4; ++n)
                    acc[m][n] = __builtin_amdgcn_mfma_f32_16x16x32_bf16(af[m], bf[n], acc[m][n], 0, 0, 0);
        }
        __syncthreads();
    }

    float bv[4];
    #pragma unroll
    for (int n = 0; n < 4; ++n) bv[n] = bias[col0 + wc * 64 + n * 16 + fr];

    if (!FUSE) {
        #pragma unroll
        for (int m = 0; m < 4; ++m) {
            #pragma unroll
            for (int j = 0; j < 4; ++j) {
                int row = row0 + wr * 64 + m * 16 + fq * 4 + j;
                if (row >= N_NODES) continue;
                float sc = dinv[row];
                unsigned short* o = Cb + (size_t)row * HID + col0 + wc * 64;
                #pragma unroll
                for (int n = 0; n < 4; ++n) {
                    float v = fmaxf(acc[m][n][j] + bv[n], 0.f) * sc;
                    o[n * 16 + fr] = f2bf(v);
                }
            }
        }
    } else {
        int gm[4][4];
        #pragma unroll
        for (int m = 0; m < 4; ++m)
            #pragma unroll
            for (int j = 0; j < 4; ++j) {
                int row = row0 + wr * 64 + m * 16 + fq * 4 + j;
                gm[m][j] = (row < N_NODES) ? batch[row] : -1;
                #pragma unroll
                for (int n = 0; n < 4; ++n)
                    acc[m][n][j] = fmaxf(acc[m][n][j] + bv[n], 0.f);
            }
        int rhi = row0 + 127; if (rhi >= N_NODES) rhi = N_NODES - 1;
        int glo = batch[row0], ghi = batch[rhi];
        for (int g = glo; g <= ghi; ++g) {
            if (t < 128) red[t] = 0.f;
            __syncthreads();
            #pragma unroll
            for (int n = 0; n < 4; ++n) {
                float s = 0.f;
                #pragma unroll
                for (int m = 0; m < 4; ++m)
                    #pragma unroll
                    for (int j = 0; j < 4; ++j)
                        if (gm[m][j] == g) s += acc[m][n][j];
                if (s != 0.f) atomicAdd(&red[wc * 64 + n * 16 + fr], s);
            }
            __syncthreads();
            if (t < 128 && red[t] != 0.f)
                atomicAdd(&pooled[g * HID + col0 + t], red[t]);
            __syncthreads();
        }
    }
}

// ---------------- final FC (per-graph counts via inline binary search) ----------------
__global__ void k_final(const float* __restrict__ pooled, const int* __restrict__ batch,
                        const float* __restrict__ Wfc, const float* __restrict__ bfc,
                        float* __restrict__ out) {
    int t = blockIdx.x * blockDim.x + threadIdx.x;
    if (t >= N_GRAPHS * OUT_F) return;
    int g = t / OUT_F, o = t % OUT_F;
    int lo = 0, hi = N_NODES;
    while (lo < hi) { int mid = (lo + hi) >> 1; if (batch[mid] < g) lo = mid + 1; else hi = mid; }
    int a = lo;
    lo = 0; hi = N_NODES;
    while (lo < hi) { int mid = (lo + hi) >> 1; if (batch[mid] < g + 1) lo = mid + 1; else hi = mid; }
    float inv = 1.0f / fmaxf((float)(lo - a), 1.0f);
    float s = 0.f;
    for (int k = 0; k < HID; ++k) s += pooled[g * HID + k] * Wfc[o * HID + k];
    out[t] = s * inv + bfc[o];
}

extern "C" void kernel_launch(void* const* d_in, const int* in_sizes, int n_in,
                              void* d_out, int out_size, void* d_ws, size_t ws_size,
                              hipStream_t stream) {
    const float* x    = (const float*)d_in[0];
    const int*   ei   = (const int*)d_in[1];
    const int*   bat  = (const int*)d_in[2];
    const float* W1   = (const float*)d_in[3];
    const float* b1   = (const float*)d_in[4];
    const float* W2   = (const float*)d_in[5];
    const float* b2   = (const float*)d_in[6];
    const float* Wfc  = (const float*)d_in[7];
    const float* bfc  = (const float*)d_in[8];
    float* out = (float*)d_out;

    const int* src = ei;
    const int* dst = ei + N_EDGES;

    float* ws = (float*)d_ws;
    float* dinv    = ws + 0;                 // 100096
    float* pooled  = ws + 100096;            // 16384 (+128 pad)
    int*   cnt     = (int*)(ws + 116608);    // 100096
    int*   rowptr  = (int*)(ws + 216704);    // 100224
    int*   bsum    = (int*)(ws + 316928);    // 128
    int*   plocal  = (int*)(ws + 317056);    // 1600000
    int*   col     = (int*)(ws + 1917056);   // 1600000
    unsigned short* W1b = (unsigned short*)(ws + 3517056);   // 32768 bf16 -> 16384 f
    unsigned short* W2b = (unsigned short*)(ws + 3533440);   // 65536 bf16 -> 32768 f
    unsigned short* xb  = (unsigned short*)(ws + 3566208);   // 100000*128 bf16
    unsigned short* h1b = (unsigned short*)(ws + 9966208);   // 100000*256 bf16
    unsigned short* aggb = (unsigned short*)(ws + 22766208); // 100000*256 bf16

    const int B = 256;

    // zero: pooled (+pad) .. cnt  (rowptr/bsum fully written by scan1)
    hipMemsetAsync(pooled, 0, (size_t)(216704 - 100096) * 4, stream);

    k_countp<<<(N_EDGES + B - 1) / B, B, 0, stream>>>(dst, cnt, plocal);
    k_scan1<<<SCAN_NB, SCAN_B, 0, stream>>>(cnt, rowptr, bsum, dinv);
    k_scan23<<<(N_NODES + B - 1) / B, B, 0, stream>>>(rowptr, bsum);
    {
        int tot = NX8 + HID * IN_F / 8 + HID * HID / 8;
        k_cvt<<<(tot + B - 1) / B, B, 0, stream>>>(x, dinv, xb, W1, W1b, W2, W2b);
    }
    k_fill2<<<(N_EDGES + B - 1) / B, B, 0, stream>>>(src, dst, rowptr, plocal, col);

    // layer 1: aggb = bf16(A_hat @ x), h1b = bf16(relu(aggb@W1^T+b1)*dinv)
    k_aggv<IN_F, 4><<<(N_NODES + 3) / 4, 256, 0, stream>>>(xb, dinv, rowptr, cnt, col, aggb);
    {
        dim3 grid((N_NODES + 127) / 128, HID / 128);
        k_mgemm<IN_F, false><<<grid, 256, 0, stream>>>(aggb, W1b, b1, h1b, dinv, nullptr, nullptr);
    }

    // layer 2: aggb = bf16(A_hat @ h1), pooled += relu(aggb@W2^T+b2) segment-reduced
    k_aggv<HID, 4><<<(N_NODES + 3) / 4, 256, 0, stream>>>(h1b, dinv, rowptr, cnt, col, aggb);
    {
        dim3 grid((N_NODES + 127) / 128, HID / 128);
        k_mgemm<HID, true><<<grid, 256, 0, stream>>>(aggb, W2b, b2, nullptr, nullptr, bat, pooled);
    }

    k_final<<<(N_GRAPHS * OUT_F + B - 1) / B, B, 0, stream>>>(pooled, bat, Wfc, bfc, out);
}